// Round 2
// baseline (236.132 us; speedup 1.0000x reference)
//
#include <hip/hip_runtime.h>
#include <hip/hip_bf16.h>
#include <cstdint>
#include <cstddef>

typedef __bf16 bf16x8 __attribute__((ext_vector_type(8)));
typedef __bf16 bf16x4 __attribute__((ext_vector_type(4)));
typedef __bf16 bf16x2 __attribute__((ext_vector_type(2)));
typedef float  f32x4  __attribute__((ext_vector_type(4)));
typedef float  f32x2  __attribute__((ext_vector_type(2)));

#define T_SEQ 2048
#define CDIM  2048
#define NH    16
#define NG    4
#define DH    128

// ---------------- cast f32 -> bf16 (contiguous) ----------------
__global__ __launch_bounds__(256) void cast_bf16_kernel(const float* __restrict__ in,
                                                        __bf16* __restrict__ out) {
  size_t i = ((size_t)blockIdx.x * 256 + threadIdx.x) * 8;
  f32x4 a = *(const f32x4*)(in + i);
  f32x4 b = *(const f32x4*)(in + i + 4);
  bf16x8 o;
#pragma unroll
  for (int j = 0; j < 4; ++j) { o[j] = (__bf16)a[j]; o[4 + j] = (__bf16)b[j]; }
  *(bf16x8*)(out + i) = o;
}

// ---------------- transpose + cast: W[K][N] f32 -> Wt[N][K] bf16 ----------------
__global__ __launch_bounds__(256) void transpose_cast_kernel(const float* __restrict__ W,
                                                             __bf16* __restrict__ Wt,
                                                             int K, int N) {
  __shared__ __bf16 tile[64][68];  // pad 68: stride 136B = 34 words -> bank drift 2
  int k0 = blockIdx.x * 64, n0 = blockIdx.y * 64;
  int tid = threadIdx.x;
  int c4 = (tid & 15) * 4, r = tid >> 4;
#pragma unroll
  for (int rr = 0; rr < 4; ++rr) {
    int row = r + rr * 16;
    f32x4 v = *(const f32x4*)(W + (size_t)(k0 + row) * N + n0 + c4);
#pragma unroll
    for (int j = 0; j < 4; ++j) tile[row][c4 + j] = (__bf16)v[j];
  }
  __syncthreads();
  int n = tid >> 2, seg = tid & 3;
  __bf16 vals[16];
#pragma unroll
  for (int j = 0; j < 16; ++j) vals[j] = tile[seg * 16 + j][n];
  __bf16* dst = Wt + (size_t)(n0 + n) * K + k0 + seg * 16;
  *(bf16x8*)(dst)     = *(bf16x8*)(&vals[0]);
  *(bf16x8*)(dst + 8) = *(bf16x8*)(&vals[8]);
}

// ---------------- RoPE (interleaved) + scatter q,k to [head][T][D] bf16 ----------------
__global__ __launch_bounds__(256) void rope_scatter_kernel(const float* __restrict__ qkv,
    const float* __restrict__ cosb, const float* __restrict__ sinb,
    __bf16* __restrict__ qb, __bf16* __restrict__ kb) {
  int t = blockIdx.x;
  int w = threadIdx.x >> 6, l = threadIdx.x & 63;
  float c = cosb[t * 64 + l], s = sinb[t * 64 + l];
#pragma unroll
  for (int it = 0; it < 5; ++it) {
    int slot = w + it * 4;           // 20 slots: g*5 + j, j<4 => q head g*4+j, j==4 => k group g
    int g = slot / 5, j = slot % 5;
    const float* src = qkv + (size_t)t * 3072 + g * 768 + j * 128;
    f32x2 xv = *(const f32x2*)(src + 2 * l);
    float o1 = xv[0] * c - xv[1] * s;
    float o2 = xv[0] * s + xv[1] * c;
    __bf16* dst = (j < 4) ? (qb + ((size_t)(g * 4 + j) * T_SEQ + t) * DH)
                          : (kb + ((size_t)g * T_SEQ + t) * DH);
    dst[2 * l]     = (__bf16)o1;
    dst[2 * l + 1] = (__bf16)o2;
  }
}

// ---------------- v transpose: qkv v-section [t][d] f32 -> vtb[g][d][t] bf16 ----------------
__global__ __launch_bounds__(256) void v_transpose_kernel(const float* __restrict__ qkv,
                                                          __bf16* __restrict__ vtb) {
  __shared__ float vt[64][129];
  int g = blockIdx.x, t0 = blockIdx.y * 64;
  int tid = threadIdx.x;
#pragma unroll
  for (int it = 0; it < 8; ++it) {
    int q = it * 256 + tid;
    int tt = q >> 5, dq = q & 31;
    f32x4 v = *(const f32x4*)(qkv + (size_t)(t0 + tt) * 3072 + g * 768 + 640 + dq * 4);
#pragma unroll
    for (int j = 0; j < 4; ++j) vt[tt][dq * 4 + j] = v[j];
  }
  __syncthreads();
  int d = tid >> 1, half = tid & 1;
  __bf16 outv[32];
#pragma unroll
  for (int j = 0; j < 32; ++j) outv[j] = (__bf16)vt[half * 32 + j][d];
  __bf16* dst = vtb + ((size_t)g * DH + d) * T_SEQ + t0 + half * 32;
#pragma unroll
  for (int q4 = 0; q4 < 4; ++q4) *(bf16x8*)(dst + q4 * 8) = *(bf16x8*)(&outv[q4 * 8]);
}

// ---------------- GEMM: C[M][N] = A[M][K] * Bt[N][K]^T, bf16 MFMA, f32 accum ----------------
// MODE 0: store f32.  MODE 1: store silu(z) as bf16.
template<int MODE>
__global__ __launch_bounds__(256) void gemm_bt_kernel(const __bf16* __restrict__ A,
    const __bf16* __restrict__ Bt, void* __restrict__ Cout, int M, int N, int K) {
  __shared__ __bf16 Asb[128 * 32];
  __shared__ __bf16 Bsb[128 * 32];
  int m0 = blockIdx.x * 128, n0 = blockIdx.y * 128;
  int tid = threadIdx.x;
  int w = tid >> 6, l = tid & 63;
  int wr = w >> 1, wc = w & 1;
  int lr = l & 15, lg = l >> 4;
  int nk = K >> 5;
  f32x4 acc[4][4] = {};
  bf16x8 ra[2], rb[2];
  const __bf16* Ab = A + (size_t)m0 * K;
  const __bf16* Bb = Bt + (size_t)n0 * K;
#pragma unroll
  for (int c = 0; c < 2; ++c) {
    int gi = tid + c * 256;
    ra[c] = *(const bf16x8*)(Ab + (size_t)(gi >> 2) * K + (gi & 3) * 8);
    rb[c] = *(const bf16x8*)(Bb + (size_t)(gi >> 2) * K + (gi & 3) * 8);
  }
  for (int kt = 0; kt < nk; ++kt) {
    __syncthreads();                       // prior compute done reading LDS
#pragma unroll
    for (int c = 0; c < 2; ++c) {
      int gi = tid + c * 256;
      *(bf16x8*)(&Asb[gi * 8]) = ra[c];
      *(bf16x8*)(&Bsb[gi * 8]) = rb[c];
    }
    if (kt + 1 < nk) {
      int k0 = (kt + 1) << 5;
#pragma unroll
      for (int c = 0; c < 2; ++c) {
        int gi = tid + c * 256;
        ra[c] = *(const bf16x8*)(Ab + (size_t)(gi >> 2) * K + k0 + (gi & 3) * 8);
        rb[c] = *(const bf16x8*)(Bb + (size_t)(gi >> 2) * K + k0 + (gi & 3) * 8);
      }
    }
    __syncthreads();
    bf16x8 av[4], bv[4];
#pragma unroll
    for (int i = 0; i < 4; ++i) {
      av[i] = *(const bf16x8*)(&Asb[(wr * 64 + i * 16 + lr) * 32 + lg * 8]);
      bv[i] = *(const bf16x8*)(&Bsb[(wc * 64 + i * 16 + lr) * 32 + lg * 8]);
    }
#pragma unroll
    for (int i = 0; i < 4; ++i)
#pragma unroll
      for (int j = 0; j < 4; ++j)
        acc[i][j] = __builtin_amdgcn_mfma_f32_16x16x32_bf16(av[i], bv[j], acc[i][j], 0, 0, 0);
  }
#pragma unroll
  for (int i = 0; i < 4; ++i) {
#pragma unroll
    for (int j = 0; j < 4; ++j) {
#pragma unroll
      for (int r = 0; r < 4; ++r) {
        size_t row = (size_t)m0 + wr * 64 + i * 16 + lg * 4 + r;
        size_t col = (size_t)n0 + wc * 64 + j * 16 + lr;
        float z = acc[i][j][r];
        if (MODE == 0) {
          ((float*)Cout)[row * N + col] = z;
        } else {
          float sv = z / (1.0f + expf(-z));
          ((__bf16*)Cout)[row * N + col] = (__bf16)sv;
        }
      }
    }
  }
}

// ---------------- retention attention: y[h][t][d] = sum_s (q.k^T*scale*decay) v ----------------
__global__ __launch_bounds__(256) void attn_kernel(const __bf16* __restrict__ qb,
    const __bf16* __restrict__ kb, const __bf16* __restrict__ vtb, float* __restrict__ y) {
  __shared__ __bf16 kl[64 * 128];       // [s][d], XOR-swizzled
  __shared__ __bf16 vl[128 * 64];       // [d][s], XOR-swizzled
  __shared__ __bf16 pl[4][16 * 64];     // per-wave P [t][s], XOR-swizzled
  int h = blockIdx.x >> 5, qt = blockIdx.x & 31;
  int g = h >> 2;
  int w = threadIdx.x >> 6, l = threadIdx.x & 63;
  int lr = l & 15, lg = l >> 4;
  int t0b = qt * 64;
  int t0 = t0b + w * 16;
  bf16x8 qf[4];
#pragma unroll
  for (int kbk = 0; kbk < 4; ++kbk)
    qf[kbk] = *(const bf16x8*)(qb + ((size_t)h * T_SEQ + t0 + lr) * DH + kbk * 32 + lg * 8);
  float gamma = 1.0f - exp2f(-5.0f - (float)h);
  float l2g = log2f(gamma);
  const float scale = 0.088388347648318447f;  // 1/sqrt(128)
  f32x4 acc[8] = {};
  for (int st = 0; st <= qt; ++st) {
    int s0 = st * 64;
    float mind = (float)(t0b - (s0 + 63));
    if (mind > 0.0f && mind * l2g < -25.0f) continue;   // block-uniform skip: decay < 2^-25
    // stage k tile [64][128] and v^T tile [128][64]
#pragma unroll
    for (int it = 0; it < 4; ++it) {
      int fg = it * 256 + threadIdx.x;
      {
        int ss = fg >> 4, gr = fg & 15;
        bf16x8 kv = *(const bf16x8*)(kb + ((size_t)g * T_SEQ + s0 + ss) * DH + gr * 8);
        *(bf16x8*)((char*)kl + ss * 256 + ((gr * 16) ^ ((ss & 7) << 4))) = kv;
      }
      {
        int d = fg >> 3, gv = fg & 7;
        bf16x8 vv = *(const bf16x8*)(vtb + ((size_t)g * DH + d) * T_SEQ + s0 + gv * 8);
        *(bf16x8*)((char*)vl + d * 128 + ((gv * 16) ^ ((d & 7) << 4))) = vv;
      }
    }
    __syncthreads();
    // QK^T -> scale * decay -> P (bf16, to LDS)
#pragma unroll
    for (int sc = 0; sc < 4; ++sc) {
      f32x4 p = {0.f, 0.f, 0.f, 0.f};
      int srow = sc * 16 + lr;
#pragma unroll
      for (int kbk = 0; kbk < 4; ++kbk) {
        bf16x8 kf = *(const bf16x8*)((char*)kl + srow * 256 +
                                     ((kbk * 64 + lg * 16) ^ ((srow & 7) << 4)));
        p = __builtin_amdgcn_mfma_f32_16x16x32_bf16(qf[kbk], kf, p, 0, 0, 0);
      }
#pragma unroll
      for (int r = 0; r < 4; ++r) {
        int tl = lg * 4 + r;
        int diff = (t0 + tl) - (s0 + srow);
        float val = 0.0f;
        if (diff >= 0) val = p[r] * scale * exp2f((float)diff * l2g);
        *(__bf16*)((char*)(pl[w]) + tl * 128 +
                   (((sc * 16 + lr) * 2) ^ ((tl & 7) << 4))) = (__bf16)val;
      }
    }
    // PV: y += P @ V
    bf16x8 pa[2];
#pragma unroll
    for (int kc = 0; kc < 2; ++kc)
      pa[kc] = *(const bf16x8*)((char*)(pl[w]) + lr * 128 +
                                ((kc * 64 + lg * 16) ^ ((lr & 7) << 4)));
#pragma unroll
    for (int dc = 0; dc < 8; ++dc) {
#pragma unroll
      for (int kc = 0; kc < 2; ++kc) {
        int vrow = dc * 16 + lr;
        bf16x8 vf = *(const bf16x8*)((char*)vl + vrow * 128 +
                                     ((kc * 64 + lg * 16) ^ ((vrow & 7) << 4)));
        acc[dc] = __builtin_amdgcn_mfma_f32_16x16x32_bf16(pa[kc], vf, acc[dc], 0, 0, 0);
      }
    }
    __syncthreads();
  }
#pragma unroll
  for (int dc = 0; dc < 8; ++dc)
#pragma unroll
    for (int r = 0; r < 4; ++r)
      y[((size_t)h * T_SEQ + t0 + lg * 4 + r) * DH + dc * 16 + lr] = acc[dc][r];
}

// ---------------- RMS norm over D per (h,t) + gate multiply:
//   ynorm_gated[t][h*128+d] = (y*rsqrt(mean(y^2)+eps)) * silu_gate[t][h*128+d]  (bf16)
__global__ __launch_bounds__(256) void rms_gate_kernel(const float* __restrict__ y,
                                                       const __bf16* __restrict__ gateb,
                                                       __bf16* __restrict__ ynormb) {
  int f = blockIdx.x * 4 + (threadIdx.x >> 6);   // row = h*2048 + t
  int l = threadIdx.x & 63;
  int h = f >> 11, t = f & 2047;
  const float* row = y + (size_t)f * DH;
  f32x2 v = *(const f32x2*)(row + 2 * l);
  float ss = v[0] * v[0] + v[1] * v[1];
#pragma unroll
  for (int o = 32; o > 0; o >>= 1) ss += __shfl_xor(ss, o, 64);
  float r = rsqrtf(ss * (1.0f / 128.0f) + 1e-5f);
  size_t base = (size_t)t * CDIM + h * DH + 2 * l;
  bf16x2 gv = *(const bf16x2*)(gateb + base);
  bf16x2 o;
  o[0] = (__bf16)(v[0] * r * (float)gv[0]);
  o[1] = (__bf16)(v[1] * r * (float)gv[1]);
  *(bf16x2*)(ynormb + base) = o;
}

extern "C" void kernel_launch(void* const* d_in, const int* in_sizes, int n_in,
                              void* d_out, int out_size, void* d_ws, size_t ws_size,
                              hipStream_t stream) {
  const float* x    = (const float*)d_in[0];
  const float* cosb = (const float*)d_in[1];
  const float* sinb = (const float*)d_in[2];
  // d_in[3] = mask (268MB) -- computed analytically instead, never read
  const float* Wr   = (const float*)d_in[4];
  const float* Wg   = (const float*)d_in[5];
  const float* Wp   = (const float*)d_in[6];

  char* ws = (char*)d_ws;
  size_t off = 0;
  auto alloc = [&](size_t bytes) { void* p = ws + off; off += (bytes + 255) & ~(size_t)255; return p; };
  __bf16* xb     = (__bf16*)alloc((size_t)CDIM * CDIM * 2);          // 8MB
  __bf16* wrb    = (__bf16*)alloc((size_t)3072 * CDIM * 2);          // 12MB (W_reten^T)
  __bf16* wgb    = (__bf16*)alloc((size_t)CDIM * CDIM * 2);          // 8MB
  __bf16* wpb    = (__bf16*)alloc((size_t)CDIM * CDIM * 2);          // 8MB
  char*   qkvblk = (char*)  alloc((size_t)T_SEQ * 3072 * 4);         // 24MB (reused by y+ynorm)
  __bf16* qb     = (__bf16*)alloc((size_t)NH * T_SEQ * DH * 2);      // 8MB
  __bf16* kbp    = (__bf16*)alloc((size_t)NG * T_SEQ * DH * 2);      // 2MB
  __bf16* vtb    = (__bf16*)alloc((size_t)NG * DH * T_SEQ * 2);      // 2MB
  __bf16* gateb  = (__bf16*)alloc((size_t)CDIM * CDIM * 2);          // 8MB
  float*  qkv    = (float*)qkvblk;
  float*  yb     = (float*)qkvblk;                                    // alias (qkv dead by then)
  __bf16* ynormb = (__bf16*)(qkvblk + (size_t)16 * 1024 * 1024);      // alias tail of qkv block

  // 1) casts / transposes
  cast_bf16_kernel<<<2048, 256, 0, stream>>>(x, xb);
  transpose_cast_kernel<<<dim3(32, 48), 256, 0, stream>>>(Wr, wrb, 2048, 3072);
  transpose_cast_kernel<<<dim3(32, 32), 256, 0, stream>>>(Wg, wgb, 2048, 2048);
  transpose_cast_kernel<<<dim3(32, 32), 256, 0, stream>>>(Wp, wpb, 2048, 2048);
  // 2) qkv = x @ W_reten  (f32 out)
  gemm_bt_kernel<0><<<dim3(16, 24), 256, 0, stream>>>(xb, wrb, (void*)qkv, 2048, 3072, 2048);
  // 3) gate = silu(x @ W_gate) (bf16 out)
  gemm_bt_kernel<1><<<dim3(16, 16), 256, 0, stream>>>(xb, wgb, (void*)gateb, 2048, 2048, 2048);
  // 4) RoPE + scatter q,k ; transpose v
  rope_scatter_kernel<<<2048, 256, 0, stream>>>(qkv, cosb, sinb, qb, kbp);
  v_transpose_kernel<<<dim3(4, 32), 256, 0, stream>>>(qkv, vtb);
  // 5) retention attention -> y (aliases qkv block; qkv fully consumed above)
  attn_kernel<<<NH * 32, 256, 0, stream>>>(qb, kbp, vtb, yb);
  // 6) RMS norm * silu_gate -> ynorm_gated bf16 [T][C]   ((g*y) @ W_proj -- * binds left of @)
  rms_gate_kernel<<<NH * T_SEQ / 4, 256, 0, stream>>>(yb, gateb, ynormb);
  // 7) out = (g*y_norm) @ W_proj (f32 into d_out)
  gemm_bt_kernel<0><<<dim3(16, 16), 256, 0, stream>>>(ynormb, wpb, d_out, 2048, 2048, 2048);
}

// Round 3
// 232.647 us; speedup vs baseline: 1.0150x; 1.0150x over previous
//
#include <hip/hip_runtime.h>
#include <hip/hip_bf16.h>
#include <cstdint>
#include <cstddef>

typedef __bf16 bf16x8 __attribute__((ext_vector_type(8)));
typedef __bf16 bf16x4 __attribute__((ext_vector_type(4)));
typedef __bf16 bf16x2 __attribute__((ext_vector_type(2)));
typedef float  f32x4  __attribute__((ext_vector_type(4)));
typedef float  f32x2  __attribute__((ext_vector_type(2)));

#define T_SEQ 2048
#define CDIM  2048
#define NH    16
#define NG    4
#define DH    128

__device__ __forceinline__ void gl_lds16(const __bf16* g, __bf16* l) {
  __builtin_amdgcn_global_load_lds(
      (const __attribute__((address_space(1))) void*)g,
      (__attribute__((address_space(3))) void*)l, 16, 0, 0);
}

// ---------------- cast f32 -> bf16 (contiguous) ----------------
__global__ __launch_bounds__(256) void cast_bf16_kernel(const float* __restrict__ in,
                                                        __bf16* __restrict__ out) {
  size_t i = ((size_t)blockIdx.x * 256 + threadIdx.x) * 8;
  f32x4 a = *(const f32x4*)(in + i);
  f32x4 b = *(const f32x4*)(in + i + 4);
  bf16x8 o;
#pragma unroll
  for (int j = 0; j < 4; ++j) { o[j] = (__bf16)a[j]; o[4 + j] = (__bf16)b[j]; }
  *(bf16x8*)(out + i) = o;
}

// ---------------- transpose + cast: W[K][N] f32 -> Wt[N][K] bf16 ----------------
__global__ __launch_bounds__(256) void transpose_cast_kernel(const float* __restrict__ W,
                                                             __bf16* __restrict__ Wt,
                                                             int K, int N) {
  __shared__ __bf16 tile[64][68];
  int k0 = blockIdx.x * 64, n0 = blockIdx.y * 64;
  int tid = threadIdx.x;
  int c4 = (tid & 15) * 4, r = tid >> 4;
#pragma unroll
  for (int rr = 0; rr < 4; ++rr) {
    int row = r + rr * 16;
    f32x4 v = *(const f32x4*)(W + (size_t)(k0 + row) * N + n0 + c4);
#pragma unroll
    for (int j = 0; j < 4; ++j) tile[row][c4 + j] = (__bf16)v[j];
  }
  __syncthreads();
  int n = tid >> 2, seg = tid & 3;
  __bf16 vals[16];
#pragma unroll
  for (int j = 0; j < 16; ++j) vals[j] = tile[seg * 16 + j][n];
  __bf16* dst = Wt + (size_t)(n0 + n) * K + k0 + seg * 16;
  *(bf16x8*)(dst)     = *(bf16x8*)(&vals[0]);
  *(bf16x8*)(dst + 8) = *(bf16x8*)(&vals[8]);
}

// ---------------- RoPE (interleaved) + scatter q,k to [head][T][D] bf16 ----------------
__global__ __launch_bounds__(256) void rope_scatter_kernel(const float* __restrict__ qkv,
    const float* __restrict__ cosb, const float* __restrict__ sinb,
    __bf16* __restrict__ qb, __bf16* __restrict__ kb) {
  int t = blockIdx.x;
  int w = threadIdx.x >> 6, l = threadIdx.x & 63;
  float c = cosb[t * 64 + l], s = sinb[t * 64 + l];
#pragma unroll
  for (int it = 0; it < 5; ++it) {
    int slot = w + it * 4;
    int g = slot / 5, j = slot % 5;
    const float* src = qkv + (size_t)t * 3072 + g * 768 + j * 128;
    f32x2 xv = *(const f32x2*)(src + 2 * l);
    float o1 = xv[0] * c - xv[1] * s;
    float o2 = xv[0] * s + xv[1] * c;
    __bf16* dst = (j < 4) ? (qb + ((size_t)(g * 4 + j) * T_SEQ + t) * DH)
                          : (kb + ((size_t)g * T_SEQ + t) * DH);
    dst[2 * l]     = (__bf16)o1;
    dst[2 * l + 1] = (__bf16)o2;
  }
}

// ---------------- v transpose: qkv v-section [t][d] f32 -> vtb[g][d][t] bf16 ----------------
__global__ __launch_bounds__(256) void v_transpose_kernel(const float* __restrict__ qkv,
                                                          __bf16* __restrict__ vtb) {
  __shared__ float vt[64][129];
  int g = blockIdx.x, t0 = blockIdx.y * 64;
  int tid = threadIdx.x;
#pragma unroll
  for (int it = 0; it < 8; ++it) {
    int q = it * 256 + tid;
    int tt = q >> 5, dq = q & 31;
    f32x4 v = *(const f32x4*)(qkv + (size_t)(t0 + tt) * 3072 + g * 768 + 640 + dq * 4);
#pragma unroll
    for (int j = 0; j < 4; ++j) vt[tt][dq * 4 + j] = v[j];
  }
  __syncthreads();
  int d = tid >> 1, half = tid & 1;
  __bf16 outv[32];
#pragma unroll
  for (int j = 0; j < 32; ++j) outv[j] = (__bf16)vt[half * 32 + j][d];
  __bf16* dst = vtb + ((size_t)g * DH + d) * T_SEQ + t0 + half * 32;
#pragma unroll
  for (int q4 = 0; q4 < 4; ++q4) *(bf16x8*)(dst + q4 * 8) = *(bf16x8*)(&outv[q4 * 8]);
}

// ---------------- GEMM: 64x128 tile, BK=64, global_load_lds + T2 XOR swizzle ----------------
// A[M][K] bf16, Bt[N][K] bf16 (B^T layout).
// MODE 0: Cf[row*N+col] = z (f32).
// MODE 1 (fused qkv|gate): n0<3072 -> Cf[row*3072+col] f32 ; else Cg[row*2048+col-3072] = silu(z) bf16.
template<int MODE>
__global__ __launch_bounds__(256) void gemm_gl_kernel(
    const __bf16* __restrict__ A, const __bf16* __restrict__ Bt,
    float* __restrict__ Cf, __bf16* __restrict__ Cg, int M, int N, int K) {
  __shared__ __bf16 Asb[64 * 64];    // [row][64k] bf16, rows 128B, XOR-swizzled chunks
  __shared__ __bf16 Bsb[128 * 64];
  int m0 = blockIdx.x * 64, n0 = blockIdx.y * 128;
  int tid = threadIdx.x;
  int w = tid >> 6, l = tid & 63;
  int wr = w >> 1, wc = w & 1;       // wave -> (2 M-halves) x (2 N-halves)
  int lr = l & 15, lg = l >> 4;
  int nk = K >> 6;
  const __bf16* Ab = A + (size_t)m0 * K;
  const __bf16* Bb = Bt + (size_t)n0 * K;
  f32x4 acc[2][4] = {};
  for (int kt = 0; kt < nk; ++kt) {
    int k0 = kt << 6;
    // stage: linear LDS dest (chunk*16B), inverse-swizzled global source (kseg ^= row&7)
#pragma unroll
    for (int c = 0; c < 2; ++c) {
      int ca = c * 256 + tid;
      int row = ca >> 3, kseg = ca & 7;
      gl_lds16(Ab + (size_t)row * K + k0 + ((kseg ^ (row & 7)) << 3), Asb + ca * 8);
    }
#pragma unroll
    for (int c = 0; c < 4; ++c) {
      int cb = c * 256 + tid;
      int row = cb >> 3, kseg = cb & 7;
      gl_lds16(Bb + (size_t)row * K + k0 + ((kseg ^ (row & 7)) << 3), Bsb + cb * 8);
    }
    __syncthreads();   // compiler drains vmcnt(0) here -> LDS tiles ready
    bf16x8 av[2][2], bv[4][2];
#pragma unroll
    for (int i = 0; i < 2; ++i)
#pragma unroll
      for (int kk = 0; kk < 2; ++kk) {
        int row = wr * 32 + i * 16 + lr;   // row&7 == lr&7
        av[i][kk] = *(const bf16x8*)((const char*)Asb +
            ((row * 128 + kk * 64 + lg * 16) ^ ((lr & 7) << 4)));
      }
#pragma unroll
    for (int j = 0; j < 4; ++j)
#pragma unroll
      for (int kk = 0; kk < 2; ++kk) {
        int row = wc * 64 + j * 16 + lr;
        bv[j][kk] = *(const bf16x8*)((const char*)Bsb +
            ((row * 128 + kk * 64 + lg * 16) ^ ((lr & 7) << 4)));
      }
#pragma unroll
    for (int kk = 0; kk < 2; ++kk)
#pragma unroll
      for (int i = 0; i < 2; ++i)
#pragma unroll
        for (int j = 0; j < 4; ++j)
          acc[i][j] = __builtin_amdgcn_mfma_f32_16x16x32_bf16(av[i][kk], bv[j][kk],
                                                              acc[i][j], 0, 0, 0);
    __syncthreads();   // all ds_reads done before next stage overwrites
  }
#pragma unroll
  for (int i = 0; i < 2; ++i) {
    int row = m0 + wr * 32 + i * 16 + lg * 4;
#pragma unroll
    for (int j = 0; j < 4; ++j) {
      int col = n0 + wc * 64 + j * 16 + lr;
#pragma unroll
      for (int r = 0; r < 4; ++r) {
        float z = acc[i][j][r];
        if (MODE == 0) {
          Cf[(size_t)(row + r) * N + col] = z;
        } else {
          if (n0 < 3072) {
            Cf[(size_t)(row + r) * 3072 + col] = z;
          } else {
            float sv = z / (1.0f + expf(-z));
            Cg[(size_t)(row + r) * 2048 + (col - 3072)] = (__bf16)sv;
          }
        }
      }
    }
  }
}

// ---------------- retention attention: y[h][t][d] = sum_s (q.k^T*scale*decay) v ----------------
__global__ __launch_bounds__(256) void attn_kernel(const __bf16* __restrict__ qb,
    const __bf16* __restrict__ kb, const __bf16* __restrict__ vtb, float* __restrict__ y) {
  __shared__ __bf16 kl[64 * 128];       // [s][d], XOR-swizzled
  __shared__ __bf16 vl[128 * 64];       // [d][s], XOR-swizzled
  __shared__ __bf16 pl[4][16 * 64];     // per-wave P [t][s], XOR-swizzled
  int h = blockIdx.x >> 5, qt = blockIdx.x & 31;
  int g = h >> 2;
  int w = threadIdx.x >> 6, l = threadIdx.x & 63;
  int lr = l & 15, lg = l >> 4;
  int t0b = qt * 64;
  int t0 = t0b + w * 16;
  bf16x8 qf[4];
#pragma unroll
  for (int kbk = 0; kbk < 4; ++kbk)
    qf[kbk] = *(const bf16x8*)(qb + ((size_t)h * T_SEQ + t0 + lr) * DH + kbk * 32 + lg * 8);
  float gamma = 1.0f - exp2f(-5.0f - (float)h);
  float l2g = log2f(gamma);
  const float scale = 0.088388347648318447f;  // 1/sqrt(128)
  f32x4 acc[8] = {};
  for (int st = 0; st <= qt; ++st) {
    int s0 = st * 64;
    float mind = (float)(t0b - (s0 + 63));
    if (mind > 0.0f && mind * l2g < -25.0f) continue;   // decay < 2^-25: block-uniform skip
#pragma unroll
    for (int it = 0; it < 4; ++it) {
      int fg = it * 256 + threadIdx.x;
      {
        int ss = fg >> 4, gr = fg & 15;
        bf16x8 kv = *(const bf16x8*)(kb + ((size_t)g * T_SEQ + s0 + ss) * DH + gr * 8);
        *(bf16x8*)((char*)kl + ss * 256 + ((gr * 16) ^ ((ss & 7) << 4))) = kv;
      }
      {
        int d = fg >> 3, gv = fg & 7;
        bf16x8 vv = *(const bf16x8*)(vtb + ((size_t)g * DH + d) * T_SEQ + s0 + gv * 8);
        *(bf16x8*)((char*)vl + d * 128 + ((gv * 16) ^ ((d & 7) << 4))) = vv;
      }
    }
    __syncthreads();
#pragma unroll
    for (int sc = 0; sc < 4; ++sc) {
      f32x4 p = {0.f, 0.f, 0.f, 0.f};
      int srow = sc * 16 + lr;
#pragma unroll
      for (int kbk = 0; kbk < 4; ++kbk) {
        bf16x8 kf = *(const bf16x8*)((char*)kl + srow * 256 +
                                     ((kbk * 64 + lg * 16) ^ ((srow & 7) << 4)));
        p = __builtin_amdgcn_mfma_f32_16x16x32_bf16(qf[kbk], kf, p, 0, 0, 0);
      }
#pragma unroll
      for (int r = 0; r < 4; ++r) {
        int tl = lg * 4 + r;
        int diff = (t0 + tl) - (s0 + srow);
        float val = 0.0f;
        if (diff >= 0) val = p[r] * scale * exp2f((float)diff * l2g);
        *(__bf16*)((char*)(pl[w]) + tl * 128 +
                   (((sc * 16 + lr) * 2) ^ ((tl & 7) << 4))) = (__bf16)val;
      }
    }
    bf16x8 pa[2];
#pragma unroll
    for (int kc = 0; kc < 2; ++kc)
      pa[kc] = *(const bf16x8*)((char*)(pl[w]) + lr * 128 +
                                ((kc * 64 + lg * 16) ^ ((lr & 7) << 4)));
#pragma unroll
    for (int dc = 0; dc < 8; ++dc) {
#pragma unroll
      for (int kc = 0; kc < 2; ++kc) {
        int vrow = dc * 16 + lr;
        bf16x8 vf = *(const bf16x8*)((char*)vl + vrow * 128 +
                                     ((kc * 64 + lg * 16) ^ ((vrow & 7) << 4)));
        acc[dc] = __builtin_amdgcn_mfma_f32_16x16x32_bf16(pa[kc], vf, acc[dc], 0, 0, 0);
      }
    }
    __syncthreads();
  }
#pragma unroll
  for (int dc = 0; dc < 8; ++dc)
#pragma unroll
    for (int r = 0; r < 4; ++r)
      y[((size_t)h * T_SEQ + t0 + lg * 4 + r) * DH + dc * 16 + lr] = acc[dc][r];
}

// ---------------- RMS norm over D per (h,t) + gate multiply -> bf16 [T][C] ----------------
__global__ __launch_bounds__(256) void rms_gate_kernel(const float* __restrict__ y,
                                                       const __bf16* __restrict__ gateb,
                                                       __bf16* __restrict__ ynormb) {
  int f = blockIdx.x * 4 + (threadIdx.x >> 6);   // row = h*2048 + t
  int l = threadIdx.x & 63;
  int h = f >> 11, t = f & 2047;
  const float* row = y + (size_t)f * DH;
  f32x2 v = *(const f32x2*)(row + 2 * l);
  float ss = v[0] * v[0] + v[1] * v[1];
#pragma unroll
  for (int o = 32; o > 0; o >>= 1) ss += __shfl_xor(ss, o, 64);
  float r = rsqrtf(ss * (1.0f / 128.0f) + 1e-5f);
  size_t base = (size_t)t * CDIM + h * DH + 2 * l;
  bf16x2 gv = *(const bf16x2*)(gateb + base);
  bf16x2 o;
  o[0] = (__bf16)(v[0] * r * (float)gv[0]);
  o[1] = (__bf16)(v[1] * r * (float)gv[1]);
  *(bf16x2*)(ynormb + base) = o;
}

extern "C" void kernel_launch(void* const* d_in, const int* in_sizes, int n_in,
                              void* d_out, int out_size, void* d_ws, size_t ws_size,
                              hipStream_t stream) {
  const float* x    = (const float*)d_in[0];
  const float* cosb = (const float*)d_in[1];
  const float* sinb = (const float*)d_in[2];
  // d_in[3] = mask (268MB) -- computed analytically, never read
  const float* Wr   = (const float*)d_in[4];
  const float* Wg   = (const float*)d_in[5];
  const float* Wp   = (const float*)d_in[6];

  char* ws = (char*)d_ws;
  size_t off = 0;
  auto alloc = [&](size_t bytes) { void* p = ws + off; off += (bytes + 255) & ~(size_t)255; return p; };
  __bf16* xb     = (__bf16*)alloc((size_t)CDIM * CDIM * 2);          // 8MB
  __bf16* wtb    = (__bf16*)alloc((size_t)5120 * CDIM * 2);          // 20MB (W_reten^T | W_gate^T)
  __bf16* wpb    = (__bf16*)alloc((size_t)CDIM * CDIM * 2);          // 8MB
  char*   qkvblk = (char*)  alloc((size_t)T_SEQ * 3072 * 4);         // 24MB (reused by y+ynorm)
  __bf16* qb     = (__bf16*)alloc((size_t)NH * T_SEQ * DH * 2);      // 8MB
  __bf16* kbp    = (__bf16*)alloc((size_t)NG * T_SEQ * DH * 2);      // 2MB
  __bf16* vtb    = (__bf16*)alloc((size_t)NG * DH * T_SEQ * 2);      // 2MB
  __bf16* gateb  = (__bf16*)alloc((size_t)CDIM * CDIM * 2);          // 8MB
  float*  qkv    = (float*)qkvblk;
  float*  yb     = (float*)qkvblk;                                    // alias (qkv dead by then)
  __bf16* ynormb = (__bf16*)(qkvblk + (size_t)16 * 1024 * 1024);      // alias tail of qkv block

  // 1) casts / transposes (W_reten^T and W_gate^T into one contiguous [5120][2048])
  cast_bf16_kernel<<<2048, 256, 0, stream>>>(x, xb);
  transpose_cast_kernel<<<dim3(32, 48), 256, 0, stream>>>(Wr, wtb, 2048, 3072);
  transpose_cast_kernel<<<dim3(32, 32), 256, 0, stream>>>(Wg, wtb + (size_t)3072 * CDIM, 2048, 2048);
  transpose_cast_kernel<<<dim3(32, 32), 256, 0, stream>>>(Wp, wpb, 2048, 2048);
  // 2+3) fused: [qkv | silu(gate)] = x @ [W_reten | W_gate]
  gemm_gl_kernel<1><<<dim3(32, 40), 256, 0, stream>>>(xb, wtb, qkv, gateb, 2048, 5120, 2048);
  // 4) RoPE + scatter q,k ; transpose v
  rope_scatter_kernel<<<2048, 256, 0, stream>>>(qkv, cosb, sinb, qb, kbp);
  v_transpose_kernel<<<dim3(4, 32), 256, 0, stream>>>(qkv, vtb);
  // 5) retention attention -> y
  attn_kernel<<<NH * 32, 256, 0, stream>>>(qb, kbp, vtb, yb);
  // 6) RMS norm * silu_gate -> bf16 [T][C]
  rms_gate_kernel<<<NH * T_SEQ / 4, 256, 0, stream>>>(yb, gateb, ynormb);
  // 7) out = (g*y_norm) @ W_proj
  gemm_gl_kernel<0><<<dim3(32, 16), 256, 0, stream>>>(ynormb, wpb, (float*)d_out, nullptr,
                                                      2048, 2048, 2048);
}